// Round 4
// baseline (98.741 us; speedup 1.0000x reference)
//
#include <hip/hip_runtime.h>

// 1-NN (squared-L2 argmin over 500000x256 f32 keys) + dot(values[idx], query).
// Memory-bound: 512 MB of keys stream once -> ~81 us floor at 6.3 TB/s HBM
// (possibly less if L3 retains half the keys across replays).
// R4: single isolated change vs R3 -- 4 rows/iter (4 KB of plain cached loads
// in flight per wave) to hide memory latency at load-issue boundaries.

#define D 256
#define D4 (D / 4)            // 64 float4 per row == one wave-wide 1 KB load
#define BLOCK 256
#define GRID 2048             // 8 blocks/CU, 8192 waves, ~62 rows per wave

// Monotonic float->uint map (inputs are finite gaussians, no NaN).
__device__ __forceinline__ unsigned int fkey(float f) {
    unsigned int u = __float_as_uint(f);
    return (u & 0x80000000u) ? ~u : (u | 0x80000000u);
}

__device__ __forceinline__ float rowpart(float4 a, float4 qm2) {
    return a.x * (a.x + qm2.x) + a.y * (a.y + qm2.y)
         + a.z * (a.z + qm2.z) + a.w * (a.w + qm2.w);
}

__global__ __launch_bounds__(BLOCK) void nn_argmin_kernel(
    const float* __restrict__ query,
    const float* __restrict__ keys,
    unsigned long long* __restrict__ blockBest,  // d_ws, GRID entries
    int N)
{
    const int lane  = threadIdx.x & 63;
    const int wib   = threadIdx.x >> 6;               // wave in block
    const int wpb   = BLOCK >> 6;                     // waves per block
    const int gwave = blockIdx.x * wpb + wib;
    const int nwav  = GRID * wpb;

    const float4 q = reinterpret_cast<const float4*>(query)[lane];
    const float4 qm2 = make_float4(-2.f * q.x, -2.f * q.y, -2.f * q.z, -2.f * q.w);

    const int chunk = (N + nwav - 1) / nwav;
    const int r0 = gwave * chunk;
    const int r1 = min(N, r0 + chunk);

    unsigned long long myBest = 0xFFFFFFFFFFFFFFFFull;  // smaller == better

    const float4* __restrict__ k4 = reinterpret_cast<const float4*>(keys);

    int r = r0;
    // 4 rows per iteration: 4 KB of independent coalesced loads in flight,
    // 4 shuffle-reduce chains interleaved to hide ds_bpermute latency.
    for (; r + 3 < r1; r += 4) {
        float4 a0 = k4[(size_t)(r + 0) * D4 + lane];
        float4 a1 = k4[(size_t)(r + 1) * D4 + lane];
        float4 a2 = k4[(size_t)(r + 2) * D4 + lane];
        float4 a3 = k4[(size_t)(r + 3) * D4 + lane];
        float p0 = rowpart(a0, qm2);
        float p1 = rowpart(a1, qm2);
        float p2 = rowpart(a2, qm2);
        float p3 = rowpart(a3, qm2);
        #pragma unroll
        for (int off = 32; off; off >>= 1) {
            p0 += __shfl_down(p0, off, 64);
            p1 += __shfl_down(p1, off, 64);
            p2 += __shfl_down(p2, off, 64);
            p3 += __shfl_down(p3, off, 64);
        }
        if (lane == 0) {
            unsigned long long k0 = ((unsigned long long)fkey(p0) << 32) | (unsigned int)(r + 0);
            unsigned long long k1 = ((unsigned long long)fkey(p1) << 32) | (unsigned int)(r + 1);
            unsigned long long k2 = ((unsigned long long)fkey(p2) << 32) | (unsigned int)(r + 2);
            unsigned long long k3 = ((unsigned long long)fkey(p3) << 32) | (unsigned int)(r + 3);
            k0 = min(k0, k1); k2 = min(k2, k3);
            k0 = min(k0, k2);
            if (k0 < myBest) myBest = k0;
        }
    }
    for (; r < r1; ++r) {
        float4 a = k4[(size_t)r * D4 + lane];
        float pa = rowpart(a, qm2);
        #pragma unroll
        for (int off = 32; off; off >>= 1) pa += __shfl_down(pa, off, 64);
        if (lane == 0) {
            unsigned long long ka = ((unsigned long long)fkey(pa) << 32) | (unsigned int)r;
            if (ka < myBest) myBest = ka;
        }
    }

    // Block reduction in LDS, then ONE plain store per block (no atomics,
    // every slot overwritten every call -> no init dispatch needed).
    __shared__ unsigned long long s_best[wpb];
    if (lane == 0) s_best[wib] = myBest;
    __syncthreads();
    if (threadIdx.x == 0) {
        unsigned long long m = s_best[0];
        #pragma unroll
        for (int i = 1; i < wpb; ++i) m = min(m, s_best[i]);
        blockBest[blockIdx.x] = m;
    }
}

__global__ __launch_bounds__(BLOCK) void nn_finish_kernel(
    const float* __restrict__ query,
    const float* __restrict__ values,
    const unsigned long long* __restrict__ blockBest,
    float* __restrict__ out)
{
    const int tid  = threadIdx.x;
    const int lane = tid & 63;
    const int wib  = tid >> 6;

    // Min-reduce GRID packed entries (16 KB), coalesced.
    unsigned long long m = 0xFFFFFFFFFFFFFFFFull;
    #pragma unroll
    for (int i = 0; i < GRID / BLOCK; ++i)
        m = min(m, blockBest[i * BLOCK + tid]);
    #pragma unroll
    for (int off = 32; off; off >>= 1)
        m = min(m, __shfl_down(m, off, 64));

    __shared__ unsigned long long s_best[BLOCK / 64];
    __shared__ int s_idx;
    if (lane == 0) s_best[wib] = m;
    __syncthreads();
    if (tid == 0) {
        unsigned long long mm = s_best[0];
        #pragma unroll
        for (int i = 1; i < BLOCK / 64; ++i) mm = min(mm, s_best[i]);
        s_idx = (int)(mm & 0xFFFFFFFFull);
    }
    __syncthreads();

    if (tid < 64) {
        const float4 v = reinterpret_cast<const float4*>(values)[(size_t)s_idx * D4 + lane];
        const float4 q = reinterpret_cast<const float4*>(query)[lane];
        float d = v.x * q.x + v.y * q.y + v.z * q.z + v.w * q.w;
        #pragma unroll
        for (int off = 32; off; off >>= 1) d += __shfl_down(d, off, 64);
        if (lane == 0) out[0] = d;
    }
}

extern "C" void kernel_launch(void* const* d_in, const int* in_sizes, int n_in,
                              void* d_out, int out_size, void* d_ws, size_t ws_size,
                              hipStream_t stream) {
    const float* query  = (const float*)d_in[0];
    const float* keys   = (const float*)d_in[1];
    const float* values = (const float*)d_in[2];
    const int N = in_sizes[1] / D;

    unsigned long long* blockBest = (unsigned long long*)d_ws;  // 16 KB used

    nn_argmin_kernel<<<GRID, BLOCK, 0, stream>>>(query, keys, blockBest, N);
    nn_finish_kernel<<<1, BLOCK, 0, stream>>>(query, values, blockBest,
                                              (float*)d_out);
}

// Round 5
// 93.394 us; speedup vs baseline: 1.0573x; 1.0573x over previous
//
#include <hip/hip_runtime.h>

// 1-NN (squared-L2 argmin over 500000x256 f32 keys) + dot(values[idx], query).
// Memory-bound: 512 MB of keys stream once -> ~76-81 us floor at 6.3-6.7 TB/s.
// R5: single isolated change vs R3 -- wave->row mapping switched from chunked
// (8192 private 62KB streams) to strided (all waves sweep one contiguous
// 16 MB window in lockstep, like the 6.7 TB/s fill kernel's pattern) for
// DRAM page/channel locality.

#define D 256
#define D4 (D / 4)            // 64 float4 per row == one wave-wide 1 KB load
#define BLOCK 256
#define GRID 2048             // 8 blocks/CU, 32 waves/CU
#define NWAV (GRID * (BLOCK / 64))   // 8192 waves

// Monotonic float->uint map (inputs are finite gaussians, no NaN).
__device__ __forceinline__ unsigned int fkey(float f) {
    unsigned int u = __float_as_uint(f);
    return (u & 0x80000000u) ? ~u : (u | 0x80000000u);
}

__device__ __forceinline__ float rowpart(float4 a, float4 qm2) {
    return a.x * (a.x + qm2.x) + a.y * (a.y + qm2.y)
         + a.z * (a.z + qm2.z) + a.w * (a.w + qm2.w);
}

__global__ __launch_bounds__(BLOCK) void nn_argmin_kernel(
    const float* __restrict__ query,
    const float* __restrict__ keys,
    unsigned long long* __restrict__ blockBest,  // d_ws, GRID entries
    int N)
{
    const int lane  = threadIdx.x & 63;
    const int wib   = threadIdx.x >> 6;               // wave in block
    const int wpb   = BLOCK >> 6;                     // waves per block
    const int gwave = blockIdx.x * wpb + wib;

    const float4 q = reinterpret_cast<const float4*>(query)[lane];
    const float4 qm2 = make_float4(-2.f * q.x, -2.f * q.y, -2.f * q.z, -2.f * q.w);

    unsigned long long myBest = 0xFFFFFFFFFFFFFFFFull;  // smaller == better

    const float4* __restrict__ k4 = reinterpret_cast<const float4*>(keys);

    // Strided sweep: wave g handles row pairs (2g + i*2*NWAV). At any i the
    // 8192 waves collectively read one contiguous 16 MB sliding window.
    for (int r = gwave * 2; r + 1 < N; r += 2 * NWAV) {
        float4 a = k4[(size_t)(r + 0) * D4 + lane];
        float4 b = k4[(size_t)(r + 1) * D4 + lane];
        float pa = rowpart(a, qm2);
        float pb = rowpart(b, qm2);
        #pragma unroll
        for (int off = 32; off; off >>= 1) {
            pa += __shfl_down(pa, off, 64);
            pb += __shfl_down(pb, off, 64);
        }
        if (lane == 0) {
            unsigned long long ka = ((unsigned long long)fkey(pa) << 32) | (unsigned int)(r + 0);
            unsigned long long kb = ((unsigned long long)fkey(pb) << 32) | (unsigned int)(r + 1);
            ka = min(ka, kb);
            if (ka < myBest) myBest = ka;
        }
    }
    // Odd-N leftover row (dead for N=500000, kept for safety).
    if (N & 1) {
        int rl = N - 1;
        if (((rl >> 1) % NWAV) == gwave) {
            float4 a = k4[(size_t)rl * D4 + lane];
            float pa = rowpart(a, qm2);
            #pragma unroll
            for (int off = 32; off; off >>= 1) pa += __shfl_down(pa, off, 64);
            if (lane == 0) {
                unsigned long long ka = ((unsigned long long)fkey(pa) << 32) | (unsigned int)rl;
                if (ka < myBest) myBest = ka;
            }
        }
    }

    // Block reduction in LDS, then ONE plain store per block (no atomics,
    // every slot overwritten every call -> no init dispatch needed).
    __shared__ unsigned long long s_best[wpb];
    if (lane == 0) s_best[wib] = myBest;
    __syncthreads();
    if (threadIdx.x == 0) {
        unsigned long long m = s_best[0];
        #pragma unroll
        for (int i = 1; i < wpb; ++i) m = min(m, s_best[i]);
        blockBest[blockIdx.x] = m;
    }
}

__global__ __launch_bounds__(BLOCK) void nn_finish_kernel(
    const float* __restrict__ query,
    const float* __restrict__ values,
    const unsigned long long* __restrict__ blockBest,
    float* __restrict__ out)
{
    const int tid  = threadIdx.x;
    const int lane = tid & 63;
    const int wib  = tid >> 6;

    // Min-reduce GRID packed entries (16 KB), coalesced.
    unsigned long long m = 0xFFFFFFFFFFFFFFFFull;
    #pragma unroll
    for (int i = 0; i < GRID / BLOCK; ++i)
        m = min(m, blockBest[i * BLOCK + tid]);
    #pragma unroll
    for (int off = 32; off; off >>= 1)
        m = min(m, __shfl_down(m, off, 64));

    __shared__ unsigned long long s_best[BLOCK / 64];
    __shared__ int s_idx;
    if (lane == 0) s_best[wib] = m;
    __syncthreads();
    if (tid == 0) {
        unsigned long long mm = s_best[0];
        #pragma unroll
        for (int i = 1; i < BLOCK / 64; ++i) mm = min(mm, s_best[i]);
        s_idx = (int)(mm & 0xFFFFFFFFull);
    }
    __syncthreads();

    if (tid < 64) {
        const float4 v = reinterpret_cast<const float4*>(values)[(size_t)s_idx * D4 + lane];
        const float4 q = reinterpret_cast<const float4*>(query)[lane];
        float d = v.x * q.x + v.y * q.y + v.z * q.z + v.w * q.w;
        #pragma unroll
        for (int off = 32; off; off >>= 1) d += __shfl_down(d, off, 64);
        if (lane == 0) out[0] = d;
    }
}

extern "C" void kernel_launch(void* const* d_in, const int* in_sizes, int n_in,
                              void* d_out, int out_size, void* d_ws, size_t ws_size,
                              hipStream_t stream) {
    const float* query  = (const float*)d_in[0];
    const float* keys   = (const float*)d_in[1];
    const float* values = (const float*)d_in[2];
    const int N = in_sizes[1] / D;

    unsigned long long* blockBest = (unsigned long long*)d_ws;  // 16 KB used

    nn_argmin_kernel<<<GRID, BLOCK, 0, stream>>>(query, keys, blockBest, N);
    nn_finish_kernel<<<1, BLOCK, 0, stream>>>(query, values, blockBest,
                                              (float*)d_out);
}